// Round 9
// baseline (128.644 us; speedup 1.0000x reference)
//
#include <hip/hip_runtime.h>
#include <math.h>

#define NUM_E   100000
#define HIDDEN  64
#define BATCH   32
#define GAMMA_F 12.0f
#define EMB_RANGE_F 0.21875f                       // (12+2)/64
#define INV_TWO_EMB (1.0f / (2.0f * EMB_RANGE_F))  // rev = r * this = phase/(2pi)

typedef float v4f __attribute__((ext_vector_type(4)));
typedef float v2f __attribute__((ext_vector_type(2)));

// ---- packed-f32 VALU (VOP3P), byte-exact R6 helpers (R6 PASSED) ----
static __device__ __forceinline__ v2f pk_sub(v2f a, v2f b) {
    v2f d;
    asm("v_pk_add_f32 %0, %1, %2 neg_lo:[0,1] neg_hi:[0,1]"
        : "=v"(d) : "v"(a), "v"(b));
    return d;
}
static __device__ __forceinline__ v2f pk_mul(v2f a, v2f b) {
    v2f d;
    asm("v_pk_mul_f32 %0, %1, %2" : "=v"(d) : "v"(a), "v"(b));
    return d;
}
static __device__ __forceinline__ v2f pk_fma(v2f a, v2f b, v2f c) {
    v2f d;
    asm("v_pk_fma_f32 %0, %1, %2, %3" : "=v"(d) : "v"(a), "v"(b), "v"(c));
    return d;
}
// R6's scalar-accumulating sq2 (NOT R7/R8's sq2v/pk_add variant, which is
// the only element shared by the two failing rounds).
static __device__ __forceinline__ float sq2(v2f dx, v2f dy) {
    v2f sq = pk_fma(dy, dy, pk_mul(dx, dx));
    return __builtin_amdgcn_sqrtf(sq.x) + __builtin_amdgcn_sqrtf(sq.y);
}
static __device__ __forceinline__ v2f lo2(v4f v) { return __builtin_shufflevector(v, v, 0, 1); }
static __device__ __forceinline__ v2f hi2(v4f v) { return __builtin_shufflevector(v, v, 2, 3); }

// cross-lane add via DPP quad_perm (VALU pipe), R6-verified
template <int CTRL>
static __device__ __forceinline__ float dpp_xor_add(float x) {
    int y = __builtin_amdgcn_update_dpp(0, __float_as_int(x), CTRL, 0xF, 0xF, true);
    return x + __int_as_float(y);
}

// Fused kernel (R9): single dispatch.
//  - Phase prologue fused in: each lane computes its own RR/RI slice
//    (batches 4bg..4bg+3, dims 8dg..8dg+7) with kernel-A-verbatim math,
//    into the R6-verified register layout. Deletes kernel A, the d_ws
//    round-trip, and one dispatch of the constant ~72us launch gap.
//  - Tile loop: 625 blocks x 5 tiles x 4 waves x 8 entities = 100000
//    exactly. R6's 3125 short blocks churned (~30% occupancy); tiles
//    amortize the prologue 5x and keep waves resident.
//  - Compute / reduction / scratch transpose: byte-exact R6 path
//    (pk_sub chain, scalar sq2 adds, DPP xor1+xor2, shfl_xor(4),
//    row-select + stride scratch), with ONE index change: scratch
//    stride 33 -> 40. Read bank = (8*el+bA)%32 -> <=2-way (free, m136);
//    stride 33's (el+bA)%32 was 4-way = the 300k conflicts.
__global__ __launch_bounds__(256, 4) void rotate_fused_kernel(
        const int* __restrict__ facts,
        const float* __restrict__ ent,
        const float* __restrict__ rel,
        float* __restrict__ out) {
    __shared__ float s_ent[4096];          // 4 waves x 8 entity rows
    __shared__ float s_scr[4][4 * 40];     // per-wave transpose scratch

    const int t    = threadIdx.x;
    const int lane = t & 63;
    const int wv   = t >> 6;
    const int bg   = lane >> 3;            // batches 4bg..4bg+3
    const int dg   = lane & 7;             // dims 8dg..8dg+7

    // ---- fused phase prologue: RR/RI slice in registers (once per wave) ----
    v2f RR[4][4], RI[4][4];
#pragma unroll
    for (int kb = 0; kb < 4; ++kb) {
        const int b  = bg * 4 + kb;
        const int f0 = facts[b * 3 + 0];
        const int f1 = facts[b * 3 + 1];
        const float* hb = ent + (size_t)f0 * 128 + dg * 8;
        const float* rb = rel + (size_t)f1 * 64 + dg * 8;
        v4f hr0 = *(const v4f*)(hb);        // head re, dims 8dg..8dg+3
        v4f hr1 = *(const v4f*)(hb + 4);
        v4f hm0 = *(const v4f*)(hb + 64);   // head im
        v4f hm1 = *(const v4f*)(hb + 68);
        v4f rl0 = *(const v4f*)(rb);        // relation
        v4f rl1 = *(const v4f*)(rb + 4);
        float hre[8] = {hr0.x, hr0.y, hr0.z, hr0.w, hr1.x, hr1.y, hr1.z, hr1.w};
        float him[8] = {hm0.x, hm0.y, hm0.z, hm0.w, hm1.x, hm1.y, hm1.z, hm1.w};
        float rlv[8] = {rl0.x, rl0.y, rl0.z, rl0.w, rl1.x, rl1.y, rl1.z, rl1.w};
        float Rr[8], Ri[8];
#pragma unroll
        for (int d = 0; d < 8; ++d) {       // kernel-A-verbatim math
            float rev = rlv[d] * INV_TWO_EMB;
            float s = __builtin_amdgcn_sinf(rev);
            float c = __builtin_amdgcn_cosf(rev);
            Rr[d] = hre[d] * c - him[d] * s;
            Ri[d] = hre[d] * s + him[d] * c;
        }
        RR[kb][0] = (v2f){Rr[0], Rr[1]}; RR[kb][1] = (v2f){Rr[2], Rr[3]};
        RR[kb][2] = (v2f){Rr[4], Rr[5]}; RR[kb][3] = (v2f){Rr[6], Rr[7]};
        RI[kb][0] = (v2f){Ri[0], Ri[1]}; RI[kb][1] = (v2f){Ri[2], Ri[3]};
        RI[kb][2] = (v2f){Ri[4], Ri[5]}; RI[kb][3] = (v2f){Ri[6], Ri[7]};
    }

    float* lds = s_ent + wv * 1024;
    float* scr = s_scr[wv];

#pragma unroll 1
    for (int tile = 0; tile < 5; ++tile) {
        const int e0 = blockIdx.x * 160 + tile * 32 + wv * 8;

        // per-wave staging of its own 8 entity rows (R6 pattern; no barrier:
        // wave consumes only its own writes, DS ops are in-order per wave)
        {
            const v4f* g4 = (const v4f*)(ent + (size_t)e0 * 128);
            v4f* s4 = (v4f*)lds;
#pragma unroll
            for (int k = 0; k < 4; ++k) s4[k * 64 + lane] = g4[k * 64 + lane];
        }

#pragma unroll 1
        for (int grp = 0; grp < 2; ++grp) {
            float p[4][4];                 // [entity i][batch kb]

#pragma unroll
            for (int i = 0; i < 4; ++i) {
                const float* base = lds + (grp * 4 + i) * 128 + dg * 8;
                v4f er0 = *(const v4f*)(base);
                v4f er1 = *(const v4f*)(base + 4);
                v4f ei0 = *(const v4f*)(base + 64);
                v4f ei1 = *(const v4f*)(base + 68);
                v2f e2[4] = { lo2(er0), hi2(er0), lo2(er1), hi2(er1) };
                v2f i2[4] = { lo2(ei0), hi2(ei0), lo2(ei1), hi2(ei1) };
#pragma unroll
                for (int kb = 0; kb < 4; ++kb) {
                    float s0 = sq2(pk_sub(RR[kb][0], e2[0]), pk_sub(RI[kb][0], i2[0]));
                    float s1 = sq2(pk_sub(RR[kb][1], e2[1]), pk_sub(RI[kb][1], i2[1]));
                    float s2 = sq2(pk_sub(RR[kb][2], e2[2]), pk_sub(RI[kb][2], i2[2]));
                    float s3 = sq2(pk_sub(RR[kb][3], e2[3]), pk_sub(RI[kb][3], i2[3]));
                    p[i][kb] = (s0 + s1) + (s2 + s3);
                }
            }

            // full reduction over dg: DPP xor1,xor2 + shfl_xor(4) (R6-verified)
#pragma unroll
            for (int i = 0; i < 4; ++i)
#pragma unroll
                for (int kb = 0; kb < 4; ++kb) {
                    float v = p[i][kb];
                    v = dpp_xor_add<0xB1>(v);      // quad_perm [1,0,3,2]
                    v = dpp_xor_add<0x4E>(v);      // quad_perm [2,3,0,1]
                    v += __shfl_xor(v, 4, 64);
                    p[i][kb] = GAMMA_F - v;        // all lanes hold final
                }

            // transpose via scratch (stride 40), then coalesced-segment stores
            if (dg < 4) {
#pragma unroll
                for (int i = 0; i < 4; ++i) {
                    float val = (dg == 0) ? p[i][0] : (dg == 1) ? p[i][1]
                              : (dg == 2) ? p[i][2] : p[i][3];
                    scr[i * 40 + bg * 4 + dg] = val;
                }
            }
#pragma unroll
            for (int j = 0; j < 2; ++j) {
                const int b  = (lane >> 2) + 16 * j;
                const int el = lane & 3;
                float v = scr[el * 40 + b];
                out[(size_t)b * NUM_E + e0 + grp * 4 + el] = v;
            }
        }
    }
}

extern "C" void kernel_launch(void* const* d_in, const int* in_sizes, int n_in,
                              void* d_out, int out_size, void* d_ws, size_t ws_size,
                              hipStream_t stream) {
    const int*   facts = (const int*)d_in[0];
    const float* ent   = (const float*)d_in[1];
    const float* rel   = (const float*)d_in[2];
    float*       out   = (float*)d_out;

    // 625 blocks x 5 tiles x 4 waves x 8 entities = 100000 exactly
    rotate_fused_kernel<<<dim3(625), dim3(256), 0, stream>>>(
        facts, ent, rel, out);
}

// Round 10
// 122.222 us; speedup vs baseline: 1.0525x; 1.0525x over previous
//
#include <hip/hip_runtime.h>
#include <math.h>

#define NUM_E   100000
#define HIDDEN  64
#define BATCH   32
#define GAMMA_F 12.0f
#define EMB_RANGE_F 0.21875f                       // (12+2)/64
#define INV_TWO_EMB (1.0f / (2.0f * EMB_RANGE_F))  // rev = r * this = phase/(2pi)

typedef float v4f __attribute__((ext_vector_type(4)));
typedef float v2f __attribute__((ext_vector_type(2)));

// ---- packed-f32 VALU (VOP3P), byte-exact R6/R9 helpers (both PASSED) ----
static __device__ __forceinline__ v2f pk_sub(v2f a, v2f b) {
    v2f d;
    asm("v_pk_add_f32 %0, %1, %2 neg_lo:[0,1] neg_hi:[0,1]"
        : "=v"(d) : "v"(a), "v"(b));
    return d;
}
static __device__ __forceinline__ v2f pk_mul(v2f a, v2f b) {
    v2f d;
    asm("v_pk_mul_f32 %0, %1, %2" : "=v"(d) : "v"(a), "v"(b));
    return d;
}
static __device__ __forceinline__ v2f pk_fma(v2f a, v2f b, v2f c) {
    v2f d;
    asm("v_pk_fma_f32 %0, %1, %2, %3" : "=v"(d) : "v"(a), "v"(b), "v"(c));
    return d;
}
// scalar-accumulating sq2 (R6/R9-verified; the sq2v/pk_add variant is the
// common element of the two failing rounds R7/R8 — do not reintroduce)
static __device__ __forceinline__ float sq2(v2f dx, v2f dy) {
    v2f sq = pk_fma(dy, dy, pk_mul(dx, dx));
    return __builtin_amdgcn_sqrtf(sq.x) + __builtin_amdgcn_sqrtf(sq.y);
}
static __device__ __forceinline__ v2f lo2(v4f v) { return __builtin_shufflevector(v, v, 0, 1); }
static __device__ __forceinline__ v2f hi2(v4f v) { return __builtin_shufflevector(v, v, 2, 3); }

// cross-lane add via DPP quad_perm (VALU pipe), R6-verified
template <int CTRL>
static __device__ __forceinline__ float dpp_xor_add(float x) {
    int y = __builtin_amdgcn_update_dpp(0, __float_as_int(x), CTRL, 0xF, 0xF, true);
    return x + __int_as_float(y);
}

// Fused kernel (R10) = R9 compute path with two fixes the counters demanded:
//  - grid 3125 x 1 tile (R9's 625x5 dropped occupancy 30->17: more blocks
//    win; "block churn" theory was falsified).
//  - __launch_bounds__(256, 3): ~170-VGPR budget. R9's (256,4)=128 cap made
//    the compiler SPILL the 64-VGPR RR/RI slice to scratch (VGPR_Count=64,
//    WRITE_SIZE 12.5->15.1 MB). With 3 waves/SIMD the slice stays resident.
__global__ __launch_bounds__(256, 3) void rotate_fused_kernel(
        const int* __restrict__ facts,
        const float* __restrict__ ent,
        const float* __restrict__ rel,
        float* __restrict__ out) {
    __shared__ float s_ent[4096];          // 4 waves x 8 entity rows
    __shared__ float s_scr[4][4 * 40];     // per-wave transpose scratch

    const int t    = threadIdx.x;
    const int lane = t & 63;
    const int wv   = t >> 6;
    const int bg   = lane >> 3;            // batches 4bg..4bg+3
    const int dg   = lane & 7;             // dims 8dg..8dg+7

    // ---- fused phase prologue: RR/RI slice in registers (once per wave) ----
    v2f RR[4][4], RI[4][4];
#pragma unroll
    for (int kb = 0; kb < 4; ++kb) {
        const int b  = bg * 4 + kb;
        const int f0 = facts[b * 3 + 0];
        const int f1 = facts[b * 3 + 1];
        const float* hb = ent + (size_t)f0 * 128 + dg * 8;
        const float* rb = rel + (size_t)f1 * 64 + dg * 8;
        v4f hr0 = *(const v4f*)(hb);        // head re, dims 8dg..8dg+3
        v4f hr1 = *(const v4f*)(hb + 4);
        v4f hm0 = *(const v4f*)(hb + 64);   // head im
        v4f hm1 = *(const v4f*)(hb + 68);
        v4f rl0 = *(const v4f*)(rb);        // relation
        v4f rl1 = *(const v4f*)(rb + 4);
        float hre[8] = {hr0.x, hr0.y, hr0.z, hr0.w, hr1.x, hr1.y, hr1.z, hr1.w};
        float him[8] = {hm0.x, hm0.y, hm0.z, hm0.w, hm1.x, hm1.y, hm1.z, hm1.w};
        float rlv[8] = {rl0.x, rl0.y, rl0.z, rl0.w, rl1.x, rl1.y, rl1.z, rl1.w};
        float Rr[8], Ri[8];
#pragma unroll
        for (int d = 0; d < 8; ++d) {       // kernel-A-verbatim math
            float rev = rlv[d] * INV_TWO_EMB;
            float s = __builtin_amdgcn_sinf(rev);
            float c = __builtin_amdgcn_cosf(rev);
            Rr[d] = hre[d] * c - him[d] * s;
            Ri[d] = hre[d] * s + him[d] * c;
        }
        RR[kb][0] = (v2f){Rr[0], Rr[1]}; RR[kb][1] = (v2f){Rr[2], Rr[3]};
        RR[kb][2] = (v2f){Rr[4], Rr[5]}; RR[kb][3] = (v2f){Rr[6], Rr[7]};
        RI[kb][0] = (v2f){Ri[0], Ri[1]}; RI[kb][1] = (v2f){Ri[2], Ri[3]};
        RI[kb][2] = (v2f){Ri[4], Ri[5]}; RI[kb][3] = (v2f){Ri[6], Ri[7]};
    }

    float* lds = s_ent + wv * 1024;
    float* scr = s_scr[wv];
    const int e0 = blockIdx.x * 32 + wv * 8;

    // per-wave staging of its own 8 entity rows (R6/R9 pattern; no barrier:
    // wave consumes only its own writes, DS ops are in-order per wave)
    {
        const v4f* g4 = (const v4f*)(ent + (size_t)e0 * 128);
        v4f* s4 = (v4f*)lds;
#pragma unroll
        for (int k = 0; k < 4; ++k) s4[k * 64 + lane] = g4[k * 64 + lane];
    }

#pragma unroll 1
    for (int grp = 0; grp < 2; ++grp) {
        float p[4][4];                 // [entity i][batch kb]

#pragma unroll
        for (int i = 0; i < 4; ++i) {
            const float* base = lds + (grp * 4 + i) * 128 + dg * 8;
            v4f er0 = *(const v4f*)(base);
            v4f er1 = *(const v4f*)(base + 4);
            v4f ei0 = *(const v4f*)(base + 64);
            v4f ei1 = *(const v4f*)(base + 68);
            v2f e2[4] = { lo2(er0), hi2(er0), lo2(er1), hi2(er1) };
            v2f i2[4] = { lo2(ei0), hi2(ei0), lo2(ei1), hi2(ei1) };
#pragma unroll
            for (int kb = 0; kb < 4; ++kb) {
                float s0 = sq2(pk_sub(RR[kb][0], e2[0]), pk_sub(RI[kb][0], i2[0]));
                float s1 = sq2(pk_sub(RR[kb][1], e2[1]), pk_sub(RI[kb][1], i2[1]));
                float s2 = sq2(pk_sub(RR[kb][2], e2[2]), pk_sub(RI[kb][2], i2[2]));
                float s3 = sq2(pk_sub(RR[kb][3], e2[3]), pk_sub(RI[kb][3], i2[3]));
                p[i][kb] = (s0 + s1) + (s2 + s3);
            }
        }

        // full reduction over dg: DPP xor1,xor2 + shfl_xor(4) (R6/R9-verified)
#pragma unroll
        for (int i = 0; i < 4; ++i)
#pragma unroll
            for (int kb = 0; kb < 4; ++kb) {
                float v = p[i][kb];
                v = dpp_xor_add<0xB1>(v);      // quad_perm [1,0,3,2]
                v = dpp_xor_add<0x4E>(v);      // quad_perm [2,3,0,1]
                v += __shfl_xor(v, 4, 64);
                p[i][kb] = GAMMA_F - v;        // all lanes hold final
            }

        // transpose via scratch (stride 40), then coalesced-segment stores
        if (dg < 4) {
#pragma unroll
            for (int i = 0; i < 4; ++i) {
                float val = (dg == 0) ? p[i][0] : (dg == 1) ? p[i][1]
                          : (dg == 2) ? p[i][2] : p[i][3];
                scr[i * 40 + bg * 4 + dg] = val;
            }
        }
#pragma unroll
        for (int j = 0; j < 2; ++j) {
            const int b  = (lane >> 2) + 16 * j;
            const int el = lane & 3;
            float v = scr[el * 40 + b];
            out[(size_t)b * NUM_E + e0 + grp * 4 + el] = v;
        }
    }
}

extern "C" void kernel_launch(void* const* d_in, const int* in_sizes, int n_in,
                              void* d_out, int out_size, void* d_ws, size_t ws_size,
                              hipStream_t stream) {
    const int*   facts = (const int*)d_in[0];
    const float* ent   = (const float*)d_in[1];
    const float* rel   = (const float*)d_in[2];
    float*       out   = (float*)d_out;

    // 3125 blocks x 4 waves x 8 entities = 100000 exactly
    rotate_fused_kernel<<<dim3(3125), dim3(256), 0, stream>>>(
        facts, ent, rel, out);
}